// Round 1
// baseline (663.620 us; speedup 1.0000x reference)
//
#include <hip/hip_runtime.h>
#include <math.h>

#define Bn 16
#define Nn 1024
#define Dn 128
#define CAP 128   // max degree ~90 (Binomial(1023,.05) max over 16M ≈ mean 51 + 5.5σ); 128 is safe

// ---------------- K1: h = x @ W^T + b ; hA = h @ A ----------------
__global__ __launch_bounds__(128) void k_h(const float* __restrict__ x,
                                           const float* __restrict__ Ww,
                                           const float* __restrict__ Wb,
                                           const float* __restrict__ A,
                                           float* __restrict__ h,
                                           float* __restrict__ hA) {
    int row = blockIdx.x;            // b*N + n
    int t = threadIdx.x;             // 0..127
    __shared__ float xs[Dn];
    __shared__ float hs[Dn];
    xs[t] = x[(size_t)row * Dn + t];
    __syncthreads();
    float acc = Wb[t];
    const float* wr = Ww + (size_t)t * Dn;   // W_w[o][d], o = t
    #pragma unroll 8
    for (int d = 0; d < Dn; ++d) acc += xs[d] * wr[d];
    h[(size_t)row * Dn + t] = acc;
    hs[t] = acc;
    __syncthreads();
    float acc2 = 0.f;
    #pragma unroll 8
    for (int d = 0; d < Dn; ++d) acc2 += hs[d] * A[d * Dn + t];  // coalesced in t
    hA[(size_t)row * Dn + t] = acc2;
}

// ---------------- K2: init Z = N (the N-deg non-edge exp(0) terms, m=0 shift) ----------------
__global__ void k_init(float* __restrict__ Z) {
    int i = blockIdx.x * 256 + threadIdx.x;
    if (i < Bn * Nn) Z[i] = (float)Nn;
}

// ---------------- K3: build row edge lists, e_sym on edges, scatter exp(e)-1 into column Z ----------------
__global__ __launch_bounds__(256) void k_edges(const float* __restrict__ adj,
                                               const float* __restrict__ h,
                                               const float* __restrict__ hA,
                                               int* __restrict__ jidx,
                                               float* __restrict__ ev,
                                               int* __restrict__ cnt,
                                               float* __restrict__ Z) {
    int row = blockIdx.x;            // b*N + i
    int b = row >> 10;               // N = 1024
    int t = threadIdx.x;
    __shared__ float hi[Dn], hAi[Dn];
    __shared__ int ej[CAP];
    __shared__ int lcnt;
    if (t == 0) lcnt = 0;
    if (t < Dn) hi[t] = h[(size_t)row * Dn + t];
    else if (t < 2 * Dn) hAi[t - Dn] = hA[(size_t)row * Dn + (t - Dn)];
    __syncthreads();
    const float* arow = adj + (size_t)row * Nn;   // coalesced row scan
    for (int j = t; j < Nn; j += 256) {
        if (arow[j] > 0.f) {
            int p = atomicAdd(&lcnt, 1);
            if (p < CAP) ej[p] = j;
        }
    }
    __syncthreads();
    int ne = lcnt < CAP ? lcnt : CAP;
    int wid = t >> 6, lane = t & 63;
    for (int idx = wid; idx < ne; idx += 4) {     // 4 waves round-robin over edges
        int j = ej[idx];
        const float* hj  = h  + ((size_t)(b * Nn + j)) * Dn;
        const float* hAj = hA + ((size_t)(b * Nn + j)) * Dn;
        float p = hAi[lane] * hj[lane] + hi[lane] * hAj[lane]
                + hAi[lane + 64] * hj[lane + 64] + hi[lane + 64] * hAj[lane + 64];
        for (int off = 32; off > 0; off >>= 1) p += __shfl_down(p, off, 64);
        if (lane == 0) {
            float ex = expf(p);
            size_t slot = (size_t)row * CAP + idx;
            jidx[slot] = j;
            ev[slot] = ex;
            atomicAdd(&Z[b * Nn + j], ex - 1.0f);  // softmax over FIRST index -> column j stats
        }
    }
    if (t == 0) cnt[row] = ne;
}

// ---------------- K4: normalize edge weights w = exp(e)/Z_col ----------------
__global__ __launch_bounds__(128) void k_norm(const int* __restrict__ cnt,
                                              const int* __restrict__ jidx,
                                              float* __restrict__ ev,
                                              const float* __restrict__ Z) {
    int row = blockIdx.x;
    int t = threadIdx.x;             // CAP == 128
    if (t < cnt[row]) {
        size_t slot = (size_t)row * CAP + t;
        int j = jidx[slot];
        int b = row >> 10;
        ev[slot] = ev[slot] / Z[b * Nn + j];
    }
}

// ---------------- K5: one hop: az = relu(att @ src); gate; dst = c*h + (1-c)*az ----------------
__global__ __launch_bounds__(128) void k_hop(const float* __restrict__ src,
                                             const float* __restrict__ h,
                                             const int* __restrict__ jidx,
                                             const float* __restrict__ w,
                                             const int* __restrict__ cnt,
                                             const float* __restrict__ gw,
                                             const float* __restrict__ gb,
                                             float* __restrict__ dst) {
    int row = blockIdx.x;            // b*N + i
    int b = row >> 10;
    int k = threadIdx.x;             // 0..127 output dim
    __shared__ float red[Dn];
    __shared__ float sco;
    int ne = cnt[row];
    size_t base = (size_t)row * CAP;
    float az = 0.f;
    for (int idx = 0; idx < ne; ++idx) {
        int j = jidx[base + idx];        // broadcast load
        float wv = w[base + idx];        // broadcast load
        az += wv * src[((size_t)(b * Nn + j)) * Dn + k];  // coalesced 512B row read
    }
    az = fmaxf(az, 0.f);
    float hk = h[(size_t)row * Dn + k];
    red[k] = hk * gw[k] + az * gw[Dn + k];
    __syncthreads();
    if (k < 64) {
        float v = red[k] + red[k + 64];
        for (int off = 32; off > 0; off >>= 1) v += __shfl_down(v, off, 64);
        if (k == 0) sco = 1.f / (1.f + expf(-(v + gb[0])));
    }
    __syncthreads();
    float c = sco;
    dst[(size_t)row * Dn + k] = c * hk + (1.f - c) * az;
}

extern "C" void kernel_launch(void* const* d_in, const int* in_sizes, int n_in,
                              void* d_out, int out_size, void* d_ws, size_t ws_size,
                              hipStream_t stream) {
    const float* x    = (const float*)d_in[0];   // [B,N,128]
    const float* adj  = (const float*)d_in[1];   // [B,N,N]
    const float* Ww   = (const float*)d_in[2];   // [128,128]
    const float* Wb   = (const float*)d_in[3];   // [128]
    const float* A    = (const float*)d_in[4];   // [128,128]
    const float* gw   = (const float*)d_in[5];   // [1,256]
    const float* gb   = (const float*)d_in[6];   // [1]
    float* out = (float*)d_out;                  // [B,N,128] f32

    const size_t BIG = (size_t)Bn * Nn * Dn;     // 2,097,152
    float* ws  = (float*)d_ws;
    float* h   = ws;                 // 8 MB
    float* hA  = ws + BIG;           // 8 MB
    float* rA  = ws + 2 * BIG;       // 8 MB
    float* rB  = ws + 3 * BIG;       // 8 MB
    float* Z   = ws + 4 * BIG;       // 64 KB
    float* ev  = ws + 4 * BIG + 16384;            // 8 MB
    int*   cnt = (int*)(ws + 5 * BIG + 16384);    // 64 KB
    int*   jid = (int*)(ws + 5 * BIG + 2 * 16384);// 8 MB
    // total ~50.5 MB of d_ws

    int rows = Bn * Nn;  // 16384
    k_h    <<<rows, 128, 0, stream>>>(x, Ww, Wb, A, h, hA);
    k_init <<<rows / 256, 256, 0, stream>>>(Z);
    k_edges<<<rows, 256, 0, stream>>>(adj, h, hA, jid, ev, cnt, Z);
    k_norm <<<rows, 128, 0, stream>>>(cnt, jid, ev, Z);
    k_hop  <<<rows, 128, 0, stream>>>(h,  h, jid, ev, cnt, gw, gb, rA);
    k_hop  <<<rows, 128, 0, stream>>>(rA, h, jid, ev, cnt, gw, gb, rB);
    k_hop  <<<rows, 128, 0, stream>>>(rB, h, jid, ev, cnt, gw, gb, out);
}

// Round 2
// 529.191 us; speedup vs baseline: 1.2540x; 1.2540x over previous
//
#include <hip/hip_runtime.h>
#include <math.h>

#define Bn 16
#define Nn 1024
#define Dn 128

typedef unsigned short ushort;
typedef short short8 __attribute__((ext_vector_type(8)));
typedef float f32x4 __attribute__((ext_vector_type(4)));
typedef ushort us8 __attribute__((ext_vector_type(8)));

__device__ __forceinline__ ushort f2bf(float f) {
    unsigned u = __float_as_uint(f);
    u += 0x7fff + ((u >> 16) & 1);           // RTN-even
    return (ushort)(u >> 16);
}

// ---------------- K1: h = x @ W^T + b (f32 + bf16) ; hA = h @ A (bf16) ----------------
__global__ __launch_bounds__(128) void k_h(const float* __restrict__ x,
                                           const float* __restrict__ Ww,
                                           const float* __restrict__ Wb,
                                           const float* __restrict__ A,
                                           float* __restrict__ h,
                                           ushort* __restrict__ h16,
                                           ushort* __restrict__ hA16) {
    int row = blockIdx.x;            // b*N + n
    int t = threadIdx.x;             // 0..127
    __shared__ float xs[Dn];
    __shared__ float hs[Dn];
    xs[t] = x[(size_t)row * Dn + t];
    __syncthreads();
    float acc = Wb[t];
    const float* wr = Ww + (size_t)t * Dn;   // W_w[o][d], o = t
    #pragma unroll 8
    for (int d = 0; d < Dn; ++d) acc += xs[d] * wr[d];
    h[(size_t)row * Dn + t] = acc;
    h16[(size_t)row * Dn + t] = f2bf(acc);
    hs[t] = acc;
    __syncthreads();
    float acc2 = 0.f;
    #pragma unroll 8
    for (int d = 0; d < Dn; ++d) acc2 += hs[d] * A[d * Dn + t];  // coalesced in t
    hA16[(size_t)row * Dn + t] = f2bf(acc2);
}

// ---------------- K2: Z = N (non-edges contribute exp(0)=1 each; m=0 shift) ----------------
__global__ void k_zinit(float* __restrict__ Z) {
    int i = blockIdx.x * 256 + threadIdx.x;
    if (i < Bn * Nn) Z[i] = (float)Nn;
}

// ---------------- K3: dense tiled scores via MFMA: E = mask * exp(hA_i.h_j + h_i.hA_j),
//                  bf16 store; column-sum (over i) of (exp-1) atomically into Z[j] -------
__global__ __launch_bounds__(256) void k_scores(const ushort* __restrict__ h16,
                                                const ushort* __restrict__ hA16,
                                                const float* __restrict__ adj,
                                                ushort* __restrict__ E,
                                                float* __restrict__ Z) {
    int b  = blockIdx.z;
    int I0 = blockIdx.x * 64;
    int J0 = blockIdx.y * 64;
    int t = threadIdx.x, wid = t >> 6, lane = t & 63;
    int m = lane & 15, q = lane >> 4;

    const size_t hb = (size_t)b * Nn * Dn;
    int rowA = I0 + wid * 16 + m;
    const us8* pA1 = (const us8*)(hA16 + hb + (size_t)rowA * Dn);  // hA_I rows
    const us8* pA2 = (const us8*)(h16  + hb + (size_t)rowA * Dn);  // h_I rows
    const us8* pBh[4]; const us8* pBa[4];
    #pragma unroll
    for (int nt = 0; nt < 4; ++nt) {
        int rb = J0 + nt * 16 + m;
        pBh[nt] = (const us8*)(h16  + hb + (size_t)rb * Dn);
        pBa[nt] = (const us8*)(hA16 + hb + (size_t)rb * Dn);
    }

    f32x4 acc[4] = {};
    #pragma unroll
    for (int ks = 0; ks < 4; ++ks) {             // K = 128 in steps of 32
        int idx = q + ks * 4;                    // us8 units: q*8 + ks*32 elements
        short8 a1 = __builtin_bit_cast(short8, pA1[idx]);
        short8 a2 = __builtin_bit_cast(short8, pA2[idx]);
        #pragma unroll
        for (int nt = 0; nt < 4; ++nt) {
            short8 b1 = __builtin_bit_cast(short8, pBh[nt][idx]);
            short8 b2 = __builtin_bit_cast(short8, pBa[nt][idx]);
            acc[nt] = __builtin_amdgcn_mfma_f32_16x16x32_bf16(a1, b1, acc[nt], 0, 0, 0);
            acc[nt] = __builtin_amdgcn_mfma_f32_16x16x32_bf16(a2, b2, acc[nt], 0, 0, 0);
        }
    }

    __shared__ float partial[4][64];
    #pragma unroll
    for (int nt = 0; nt < 4; ++nt) {
        int col = J0 + nt * 16 + m;              // j
        float colsum = 0.f;
        #pragma unroll
        for (int r = 0; r < 4; ++r) {
            int row = I0 + wid * 16 + q * 4 + r; // i
            float mask = adj[((size_t)b * Nn + row) * Nn + col];
            float ex = __expf(acc[nt][r]);
            bool on = mask > 0.f;
            E[((size_t)b * Nn + row) * Nn + col] = f2bf(on ? ex : 0.f);
            colsum += on ? (ex - 1.0f) : 0.f;
        }
        colsum += __shfl_xor(colsum, 16, 64);    // reduce across the 4 row-quads
        colsum += __shfl_xor(colsum, 32, 64);
        if (q == 0) partial[wid][nt * 16 + m] = colsum;
    }
    __syncthreads();
    if (t < 64) {
        float s = partial[0][t] + partial[1][t] + partial[2][t] + partial[3][t];
        atomicAdd(&Z[b * Nn + J0 + t], s);
    }
}

// ---------------- K4: retZT[k][j] = src[j][k] / Z[j]  (bf16, transposed) ----------------
__global__ __launch_bounds__(256) void k_prep(const float* __restrict__ src,
                                              const float* __restrict__ Z,
                                              ushort* __restrict__ T) {
    int b = blockIdx.y;
    int j0 = blockIdx.x * 64;
    int t = threadIdx.x;
    __shared__ float ls[64][129];
    __shared__ float iz[64];
    if (t < 64) iz[t] = 1.0f / Z[b * Nn + j0 + t];
    __syncthreads();
    #pragma unroll
    for (int it = 0; it < 32; ++it) {            // 64x128 floats in
        int idx = it * 256 + t;
        int j = idx >> 7, k = idx & 127;
        ls[j][k] = src[((size_t)b * Nn + j0 + j) * Dn + k] * iz[j];
    }
    __syncthreads();
    #pragma unroll
    for (int it = 0; it < 32; ++it) {            // 128x64 bf16 out
        int idx = it * 256 + t;
        int k = idx >> 6, j = idx & 63;
        T[((size_t)b * Dn + k) * Nn + j0 + j] = f2bf(ls[j][k]);
    }
}

// ---------------- K5: hop GEMM az = E @ retZT^T, fused relu+gate+lerp ----------------
__global__ __launch_bounds__(256) void k_hop(const ushort* __restrict__ E,
                                             const ushort* __restrict__ T,
                                             const float* __restrict__ h,
                                             const float* __restrict__ gw,
                                             const float* __restrict__ gb,
                                             float* __restrict__ dst) {
    int b  = blockIdx.y;
    int I0 = blockIdx.x * 64;
    int t = threadIdx.x, wid = t >> 6, lane = t & 63;
    int m = lane & 15, q = lane >> 4;

    int rowA = I0 + wid * 16 + m;                // i
    const us8* pA = (const us8*)(E + ((size_t)b * Nn + rowA) * Nn);
    const us8* pB[8];
    #pragma unroll
    for (int nt = 0; nt < 8; ++nt)
        pB[nt] = (const us8*)(T + ((size_t)b * Dn + nt * 16 + m) * Nn);

    f32x4 acc[8] = {};
    for (int ks = 0; ks < 32; ++ks) {            // K = 1024 in steps of 32
        int idx = q + ks * 4;
        short8 a = __builtin_bit_cast(short8, pA[idx]);
        #pragma unroll
        for (int nt = 0; nt < 8; ++nt) {
            short8 bf = __builtin_bit_cast(short8, pB[nt][idx]);
            acc[nt] = __builtin_amdgcn_mfma_f32_16x16x32_bf16(a, bf, acc[nt], 0, 0, 0);
        }
    }

    float gb0 = gb[0];
    float hv[8][4];
    float gsum[4] = {0.f, 0.f, 0.f, 0.f};
    #pragma unroll
    for (int nt = 0; nt < 8; ++nt) {
        int k = nt * 16 + m;
        float w1 = gw[k], w2 = gw[Dn + k];
        #pragma unroll
        for (int r = 0; r < 4; ++r) {
            int row = I0 + wid * 16 + q * 4 + r;
            float hval = h[((size_t)b * Nn + row) * Dn + k];
            float az = fmaxf(acc[nt][r], 0.f);
            acc[nt][r] = az;
            hv[nt][r] = hval;
            gsum[r] += hval * w1 + az * w2;
        }
    }
    float c[4];
    #pragma unroll
    for (int r = 0; r < 4; ++r) {
        float v = gsum[r];
        v += __shfl_xor(v, 1, 64);
        v += __shfl_xor(v, 2, 64);
        v += __shfl_xor(v, 4, 64);
        v += __shfl_xor(v, 8, 64);               // sum over 16 lanes (k within quad)
        c[r] = 1.0f / (1.0f + __expf(-(v + gb0)));
    }
    #pragma unroll
    for (int nt = 0; nt < 8; ++nt) {
        int k = nt * 16 + m;
        #pragma unroll
        for (int r = 0; r < 4; ++r) {
            int row = I0 + wid * 16 + q * 4 + r;
            dst[((size_t)b * Nn + row) * Dn + k] = c[r] * hv[nt][r] + (1.f - c[r]) * acc[nt][r];
        }
    }
}

extern "C" void kernel_launch(void* const* d_in, const int* in_sizes, int n_in,
                              void* d_out, int out_size, void* d_ws, size_t ws_size,
                              hipStream_t stream) {
    const float* x    = (const float*)d_in[0];   // [B,N,128]
    const float* adj  = (const float*)d_in[1];   // [B,N,N]
    const float* Ww   = (const float*)d_in[2];   // [128,128]
    const float* Wb   = (const float*)d_in[3];   // [128]
    const float* A    = (const float*)d_in[4];   // [128,128]
    const float* gw   = (const float*)d_in[5];   // [1,256]
    const float* gb   = (const float*)d_in[6];   // [1]
    float* out = (float*)d_out;                  // [B,N,128] f32

    char* ws = (char*)d_ws;
    float*  h    = (float*)(ws);                          // 8 MB f32
    ushort* h16  = (ushort*)(ws + (8u << 20));            // 4 MB bf16
    ushort* hA16 = (ushort*)(ws + (12u << 20));           // 4 MB bf16
    float*  rbuf = (float*)(ws + (8u << 20));             // 8 MB f32 (aliases h16/hA16, dead after k_scores)
    ushort* E    = (ushort*)(ws + (16u << 20));           // 32 MB bf16
    ushort* T    = (ushort*)(ws + (48u << 20));           // 4 MB bf16
    float*  Z    = (float*)(ws + (52u << 20));            // 64 KB
    // total ~52.1 MB

    int rows = Bn * Nn;  // 16384
    k_h     <<<rows, 128, 0, stream>>>(x, Ww, Wb, A, h, h16, hA16);
    k_zinit <<<rows / 256, 256, 0, stream>>>(Z);
    k_scores<<<dim3(16, 16, Bn), 256, 0, stream>>>(h16, hA16, adj, E, Z);
    k_prep  <<<dim3(16, Bn), 256, 0, stream>>>(h, Z, T);          // ret0 = h
    k_hop   <<<dim3(16, Bn), 256, 0, stream>>>(E, T, h, gw, gb, rbuf);
    k_prep  <<<dim3(16, Bn), 256, 0, stream>>>(rbuf, Z, T);
    k_hop   <<<dim3(16, Bn), 256, 0, stream>>>(E, T, h, gw, gb, rbuf);
    k_prep  <<<dim3(16, Bn), 256, 0, stream>>>(rbuf, Z, T);
    k_hop   <<<dim3(16, Bn), 256, 0, stream>>>(E, T, h, gw, gb, out);
}

// Round 3
// 357.104 us; speedup vs baseline: 1.8583x; 1.4819x over previous
//
#include <hip/hip_runtime.h>
#include <math.h>

#define Bn 16
#define Nn 1024
#define Dn 128

typedef unsigned short ushort;
typedef short short8 __attribute__((ext_vector_type(8)));
typedef float f32x4 __attribute__((ext_vector_type(4)));
typedef ushort us8 __attribute__((ext_vector_type(8)));

__device__ __forceinline__ ushort f2bf(float f) {
    unsigned u = __float_as_uint(f);
    u += 0x7fff + ((u >> 16) & 1);           // RTN-even
    return (ushort)(u >> 16);
}
__device__ __forceinline__ float bf2f(ushort s) {
    return __uint_as_float(((unsigned)s) << 16);
}
__device__ __forceinline__ short8 mfma_bf16(short8 a, short8 b, f32x4 c) {
    return (short8){}; // never used; placeholder to avoid confusion
}

// ---------------- K0: split-convert weights: Ww -> Whi/Wlo (row-major),
//                  A -> AThi/ATlo (TRANSPOSED: AT[e][d] = A[d][e]) ----------------
__global__ __launch_bounds__(256) void k_wprep(const float* __restrict__ Ww,
                                               const float* __restrict__ A,
                                               ushort* __restrict__ Whi,
                                               ushort* __restrict__ Wlo,
                                               ushort* __restrict__ AThi,
                                               ushort* __restrict__ ATlo) {
    int i = blockIdx.x * 256 + threadIdx.x;   // 0..16383
    float w = Ww[i];
    ushort wh = f2bf(w);
    Whi[i] = wh;
    Wlo[i] = f2bf(w - bf2f(wh));
    int e = i >> 7, d = i & 127;
    float a = A[d * Dn + e];
    ushort ah = f2bf(a);
    AThi[i] = ah;
    ATlo[i] = f2bf(a - bf2f(ah));
}

// ---------------- K1: fused MFMA: h = x @ Ww^T + b (f32+bf16); hA = h @ A (bf16)
//                  hi/lo bf16 split => f32-quality h ----------------
__global__ __launch_bounds__(256) void k_h(const float* __restrict__ x,
                                           const float* __restrict__ Wb,
                                           const ushort* __restrict__ Whi,
                                           const ushort* __restrict__ Wlo,
                                           const ushort* __restrict__ AThi,
                                           const ushort* __restrict__ ATlo,
                                           float* __restrict__ h,
                                           ushort* __restrict__ h16,
                                           ushort* __restrict__ hA16) {
    int I0 = blockIdx.x * 16;                 // 16-row tile over 16384 global rows
    int t = threadIdx.x, w = t >> 6, lane = t & 63;
    int m = lane & 15, q = lane >> 4;

    __shared__ float hs[16][Dn + 4];          // stride 132 floats (%32==4) for bank spread

    // ---- stage 1: h-tile = x-tile @ Ww^T ----
    const float* px = x + (size_t)(I0 + m) * Dn;
    f32x4 acc0 = {0,0,0,0}, acc1 = {0,0,0,0};
    #pragma unroll
    for (int ks = 0; ks < 4; ++ks) {
        int k0 = q * 8 + ks * 32;
        float v[8]; short8 ahi, alo;
        *(float4*)(v)     = *(const float4*)(px + k0);
        *(float4*)(v + 4) = *(const float4*)(px + k0 + 4);
        #pragma unroll
        for (int j = 0; j < 8; ++j) {
            ushort hi = f2bf(v[j]);
            ahi[j] = (short)hi;
            alo[j] = (short)f2bf(v[j] - bf2f(hi));
        }
        #pragma unroll
        for (int nn = 0; nn < 2; ++nn) {
            int brow = (w * 2 + nn) * 16 + m;
            short8 bhi = __builtin_bit_cast(short8, ((const us8*)(Whi + (size_t)brow * Dn))[q + ks * 4]);
            short8 blo = __builtin_bit_cast(short8, ((const us8*)(Wlo + (size_t)brow * Dn))[q + ks * 4]);
            f32x4 acc = nn ? acc1 : acc0;
            acc = __builtin_amdgcn_mfma_f32_16x16x32_bf16(ahi, bhi, acc, 0, 0, 0);
            acc = __builtin_amdgcn_mfma_f32_16x16x32_bf16(alo, bhi, acc, 0, 0, 0);
            acc = __builtin_amdgcn_mfma_f32_16x16x32_bf16(ahi, blo, acc, 0, 0, 0);
            if (nn) acc1 = acc; else acc0 = acc;
        }
    }
    #pragma unroll
    for (int nn = 0; nn < 2; ++nn) {
        int col = (w * 2 + nn) * 16 + m;
        float bias = Wb[col];
        f32x4 acc = nn ? acc1 : acc0;
        #pragma unroll
        for (int r = 0; r < 4; ++r) {
            int rl = q * 4 + r;
            float hv = acc[r] + bias;
            size_t o = (size_t)(I0 + rl) * Dn + col;
            h[o] = hv;
            h16[o] = f2bf(hv);
            hs[rl][col] = hv;
        }
    }
    __syncthreads();

    // ---- stage 2: hA-tile = h-tile @ A  (B-operand = AT rows) ----
    f32x4 bcc0 = {0,0,0,0}, bcc1 = {0,0,0,0};
    #pragma unroll
    for (int ks = 0; ks < 4; ++ks) {
        int k0 = q * 8 + ks * 32;
        float v[8]; short8 ahi, alo;
        *(float4*)(v)     = *(const float4*)(&hs[m][k0]);
        *(float4*)(v + 4) = *(const float4*)(&hs[m][k0 + 4]);
        #pragma unroll
        for (int j = 0; j < 8; ++j) {
            ushort hi = f2bf(v[j]);
            ahi[j] = (short)hi;
            alo[j] = (short)f2bf(v[j] - bf2f(hi));
        }
        #pragma unroll
        for (int nn = 0; nn < 2; ++nn) {
            int brow = (w * 2 + nn) * 16 + m;
            short8 bhi = __builtin_bit_cast(short8, ((const us8*)(AThi + (size_t)brow * Dn))[q + ks * 4]);
            short8 blo = __builtin_bit_cast(short8, ((const us8*)(ATlo + (size_t)brow * Dn))[q + ks * 4]);
            f32x4 acc = nn ? bcc1 : bcc0;
            acc = __builtin_amdgcn_mfma_f32_16x16x32_bf16(ahi, bhi, acc, 0, 0, 0);
            acc = __builtin_amdgcn_mfma_f32_16x16x32_bf16(alo, bhi, acc, 0, 0, 0);
            acc = __builtin_amdgcn_mfma_f32_16x16x32_bf16(ahi, blo, acc, 0, 0, 0);
            if (nn) bcc1 = acc; else bcc0 = acc;
        }
    }
    #pragma unroll
    for (int nn = 0; nn < 2; ++nn) {
        int col = (w * 2 + nn) * 16 + m;
        f32x4 acc = nn ? bcc1 : bcc0;
        #pragma unroll
        for (int r = 0; r < 4; ++r) {
            int rl = q * 4 + r;
            hA16[(size_t)(I0 + rl) * Dn + col] = f2bf(acc[r]);
        }
    }
}

// ---------------- K2: Z = N (non-edges contribute exp(0)=1 each; m=0 shift) ----------------
__global__ void k_zinit(float* __restrict__ Z) {
    int i = blockIdx.x * 256 + threadIdx.x;
    if (i < Bn * Nn) Z[i] = (float)Nn;
}

// ---------------- K3: dense tiled scores via MFMA: E = mask * exp(hA_i.h_j + h_i.hA_j),
//                  bf16 store; column-sum (over i) of (exp-1) atomically into Z[j] -------
__global__ __launch_bounds__(256) void k_scores(const ushort* __restrict__ h16,
                                                const ushort* __restrict__ hA16,
                                                const float* __restrict__ adj,
                                                ushort* __restrict__ E,
                                                float* __restrict__ Z) {
    int b  = blockIdx.z;
    int I0 = blockIdx.x * 64;
    int J0 = blockIdx.y * 64;
    int t = threadIdx.x, wid = t >> 6, lane = t & 63;
    int m = lane & 15, q = lane >> 4;

    const size_t hb = (size_t)b * Nn * Dn;
    int rowA = I0 + wid * 16 + m;
    const us8* pA1 = (const us8*)(hA16 + hb + (size_t)rowA * Dn);
    const us8* pA2 = (const us8*)(h16  + hb + (size_t)rowA * Dn);
    const us8* pBh[4]; const us8* pBa[4];
    #pragma unroll
    for (int nt = 0; nt < 4; ++nt) {
        int rb = J0 + nt * 16 + m;
        pBh[nt] = (const us8*)(h16  + hb + (size_t)rb * Dn);
        pBa[nt] = (const us8*)(hA16 + hb + (size_t)rb * Dn);
    }

    f32x4 acc[4] = {};
    #pragma unroll
    for (int ks = 0; ks < 4; ++ks) {
        int idx = q + ks * 4;
        short8 a1 = __builtin_bit_cast(short8, pA1[idx]);
        short8 a2 = __builtin_bit_cast(short8, pA2[idx]);
        #pragma unroll
        for (int nt = 0; nt < 4; ++nt) {
            short8 b1 = __builtin_bit_cast(short8, pBh[nt][idx]);
            short8 b2 = __builtin_bit_cast(short8, pBa[nt][idx]);
            acc[nt] = __builtin_amdgcn_mfma_f32_16x16x32_bf16(a1, b1, acc[nt], 0, 0, 0);
            acc[nt] = __builtin_amdgcn_mfma_f32_16x16x32_bf16(a2, b2, acc[nt], 0, 0, 0);
        }
    }

    __shared__ float partial[4][64];
    #pragma unroll
    for (int nt = 0; nt < 4; ++nt) {
        int col = J0 + nt * 16 + m;
        float colsum = 0.f;
        #pragma unroll
        for (int r = 0; r < 4; ++r) {
            int row = I0 + wid * 16 + q * 4 + r;
            float mask = adj[((size_t)b * Nn + row) * Nn + col];
            float ex = __expf(acc[nt][r]);
            bool on = mask > 0.f;
            E[((size_t)b * Nn + row) * Nn + col] = f2bf(on ? ex : 0.f);
            colsum += on ? (ex - 1.0f) : 0.f;
        }
        colsum += __shfl_xor(colsum, 16, 64);
        colsum += __shfl_xor(colsum, 32, 64);
        if (q == 0) partial[wid][nt * 16 + m] = colsum;
    }
    __syncthreads();
    if (t < 64) {
        float s = partial[0][t] + partial[1][t] + partial[2][t] + partial[3][t];
        atomicAdd(&Z[b * Nn + J0 + t], s);
    }
}

// ---------------- K4: T[k][j] = src[j][k] / Z[j]  (bf16, transposed) ----------------
__global__ __launch_bounds__(256) void k_prep(const float* __restrict__ src,
                                              const float* __restrict__ Z,
                                              ushort* __restrict__ T) {
    int b = blockIdx.y;
    int j0 = blockIdx.x * 64;
    int t = threadIdx.x;
    __shared__ float ls[64][129];
    __shared__ float iz[64];
    if (t < 64) iz[t] = 1.0f / Z[b * Nn + j0 + t];
    __syncthreads();
    #pragma unroll
    for (int it = 0; it < 32; ++it) {
        int idx = it * 256 + t;
        int j = idx >> 7, k = idx & 127;
        ls[j][k] = src[((size_t)b * Nn + j0 + j) * Dn + k] * iz[j];
    }
    __syncthreads();
    #pragma unroll
    for (int it = 0; it < 32; ++it) {
        int idx = it * 256 + t;
        int k = idx >> 6, j = idx & 63;
        T[((size_t)b * Dn + k) * Nn + j0 + j] = f2bf(ls[j][k]);
    }
}

// ---------------- K5: hop GEMM az = E @ T^T (16-row tiles, 4 waves split cols),
//                  fused relu + gate + lerp ----------------
__global__ __launch_bounds__(256) void k_hop(const ushort* __restrict__ E,
                                             const ushort* __restrict__ T,
                                             const float* __restrict__ h,
                                             const float* __restrict__ gw,
                                             const float* __restrict__ gb,
                                             float* __restrict__ dst) {
    int b  = blockIdx.y;
    int I0 = blockIdx.x * 16;                 // within-batch row tile
    int t = threadIdx.x, w = t >> 6, lane = t & 63;
    int m = lane & 15, q = lane >> 4;

    const us8* pA  = (const us8*)(E + ((size_t)b * Nn + I0 + m) * Nn);
    const us8* pB0 = (const us8*)(T + ((size_t)b * Dn + (w * 2)     * 16 + m) * Nn);
    const us8* pB1 = (const us8*)(T + ((size_t)b * Dn + (w * 2 + 1) * 16 + m) * Nn);

    f32x4 acc0 = {0,0,0,0}, acc1 = {0,0,0,0};
    for (int ks = 0; ks < 32; ++ks) {
        int idx = q + ks * 4;
        short8 a = __builtin_bit_cast(short8, pA[idx]);
        acc0 = __builtin_amdgcn_mfma_f32_16x16x32_bf16(a, __builtin_bit_cast(short8, pB0[idx]), acc0, 0, 0, 0);
        acc1 = __builtin_amdgcn_mfma_f32_16x16x32_bf16(a, __builtin_bit_cast(short8, pB1[idx]), acc1, 0, 0, 0);
    }

    __shared__ float red[4][16];
    __shared__ float cs[16];
    float gb0 = gb[0];
    float hv[2][4], az[2][4];
    float gs[4] = {0.f, 0.f, 0.f, 0.f};
    #pragma unroll
    for (int nn = 0; nn < 2; ++nn) {
        int k = (w * 2 + nn) * 16 + m;
        float w1 = gw[k], w2 = gw[Dn + k];
        f32x4 acc = nn ? acc1 : acc0;
        #pragma unroll
        for (int r = 0; r < 4; ++r) {
            int row = I0 + q * 4 + r;
            float hval = h[((size_t)b * Nn + row) * Dn + k];
            float a = fmaxf(acc[r], 0.f);
            hv[nn][r] = hval;
            az[nn][r] = a;
            gs[r] += hval * w1 + a * w2;
        }
    }
    #pragma unroll
    for (int r = 0; r < 4; ++r) {
        gs[r] += __shfl_xor(gs[r], 1, 64);
        gs[r] += __shfl_xor(gs[r], 2, 64);
        gs[r] += __shfl_xor(gs[r], 4, 64);
        gs[r] += __shfl_xor(gs[r], 8, 64);    // sum over m-lanes -> wave's 32 cols
        if (m == 0) red[w][q * 4 + r] = gs[r];
    }
    __syncthreads();
    if (t < 16) {
        float v = red[0][t] + red[1][t] + red[2][t] + red[3][t];
        cs[t] = 1.0f / (1.0f + __expf(-(v + gb0)));
    }
    __syncthreads();
    #pragma unroll
    for (int nn = 0; nn < 2; ++nn) {
        int k = (w * 2 + nn) * 16 + m;
        #pragma unroll
        for (int r = 0; r < 4; ++r) {
            int row = I0 + q * 4 + r;
            float c = cs[q * 4 + r];
            dst[((size_t)b * Nn + row) * Dn + k] = c * hv[nn][r] + (1.f - c) * az[nn][r];
        }
    }
}

extern "C" void kernel_launch(void* const* d_in, const int* in_sizes, int n_in,
                              void* d_out, int out_size, void* d_ws, size_t ws_size,
                              hipStream_t stream) {
    const float* x    = (const float*)d_in[0];   // [B,N,128]
    const float* adj  = (const float*)d_in[1];   // [B,N,N]
    const float* Ww   = (const float*)d_in[2];   // [128,128]
    const float* Wb   = (const float*)d_in[3];   // [128]
    const float* A    = (const float*)d_in[4];   // [128,128]
    const float* gw   = (const float*)d_in[5];   // [1,256]
    const float* gb   = (const float*)d_in[6];   // [1]
    float* out = (float*)d_out;                  // [B,N,128] f32

    char* ws = (char*)d_ws;
    float*  h    = (float*)(ws);                          // 8 MB f32
    ushort* h16  = (ushort*)(ws + (8u << 20));            // 4 MB bf16
    ushort* hA16 = (ushort*)(ws + (12u << 20));           // 4 MB bf16
    float*  rbuf = (float*)(ws + (8u << 20));             // 8 MB f32 (aliases h16/hA16, dead after k_scores)
    ushort* E    = (ushort*)(ws + (16u << 20));           // 32 MB bf16
    ushort* T    = (ushort*)(ws + (48u << 20));           // 4 MB bf16
    float*  Z    = (float*)(ws + (52u << 20));            // 64 KB
    ushort* Whi  = (ushort*)(ws + (52u << 20) + (64u << 10));
    ushort* Wlo  = (ushort*)(ws + (52u << 20) + (96u << 10));
    ushort* AThi = (ushort*)(ws + (52u << 20) + (128u << 10));
    ushort* ATlo = (ushort*)(ws + (52u << 20) + (160u << 10));
    // total ~52.2 MB

    k_wprep <<<64, 256, 0, stream>>>(Ww, A, Whi, Wlo, AThi, ATlo);
    k_h     <<<1024, 256, 0, stream>>>(x, Wb, Whi, Wlo, AThi, ATlo, h, h16, hA16);
    k_zinit <<<64, 256, 0, stream>>>(Z);
    k_scores<<<dim3(16, 16, Bn), 256, 0, stream>>>(h16, hA16, adj, E, Z);
    k_prep  <<<dim3(16, Bn), 256, 0, stream>>>(h, Z, T);          // ret0 = h
    k_hop   <<<dim3(64, Bn), 256, 0, stream>>>(E, T, h, gw, gb, rbuf);
    k_prep  <<<dim3(16, Bn), 256, 0, stream>>>(rbuf, Z, T);
    k_hop   <<<dim3(64, Bn), 256, 0, stream>>>(E, T, h, gw, gb, rbuf);
    k_prep  <<<dim3(16, Bn), 256, 0, stream>>>(rbuf, Z, T);
    k_hop   <<<dim3(64, Bn), 256, 0, stream>>>(E, T, h, gw, gb, out);
}

// Round 4
// 320.074 us; speedup vs baseline: 2.0733x; 1.1157x over previous
//
#include <hip/hip_runtime.h>
#include <math.h>

#define Bn 16
#define Nn 1024
#define Dn 128

typedef unsigned short ushort;
typedef short short8 __attribute__((ext_vector_type(8)));
typedef float f32x4 __attribute__((ext_vector_type(4)));
typedef ushort us8 __attribute__((ext_vector_type(8)));
typedef ushort us4 __attribute__((ext_vector_type(4)));

__device__ __forceinline__ ushort f2bf(float f) {
    unsigned u = __float_as_uint(f);
    u += 0x7fff + ((u >> 16) & 1);           // RTN-even
    return (ushort)(u >> 16);
}
__device__ __forceinline__ float bf2f(ushort s) {
    return __uint_as_float(((unsigned)s) << 16);
}

// ---------------- K0: split weights (Ww->hi/lo, A^T->hi/lo) + Z init ----------------
__global__ __launch_bounds__(256) void k_wprep(const float* __restrict__ Ww,
                                               const float* __restrict__ A,
                                               ushort* __restrict__ Whi,
                                               ushort* __restrict__ Wlo,
                                               ushort* __restrict__ AThi,
                                               ushort* __restrict__ ATlo,
                                               float* __restrict__ Z) {
    int i = blockIdx.x * 256 + threadIdx.x;   // 0..16383
    float w = Ww[i];
    ushort wh = f2bf(w);
    Whi[i] = wh;
    Wlo[i] = f2bf(w - bf2f(wh));
    int e = i >> 7, d = i & 127;
    float a = A[d * Dn + e];
    ushort ah = f2bf(a);
    AThi[i] = ah;
    ATlo[i] = f2bf(a - bf2f(ah));
    Z[i] = (float)Nn;                         // non-edge exp(0) mass, m=0 shift
}

// ---------------- K1: fused MFMA: h = x @ Ww^T + b ; hA = h @ A (hi/lo split) ----------------
__global__ __launch_bounds__(256) void k_h(const float* __restrict__ x,
                                           const float* __restrict__ Wb,
                                           const ushort* __restrict__ Whi,
                                           const ushort* __restrict__ Wlo,
                                           const ushort* __restrict__ AThi,
                                           const ushort* __restrict__ ATlo,
                                           float* __restrict__ h,
                                           ushort* __restrict__ h16,
                                           ushort* __restrict__ hA16) {
    int I0 = blockIdx.x * 16;
    int t = threadIdx.x, w = t >> 6, lane = t & 63;
    int m = lane & 15, q = lane >> 4;

    __shared__ float hs[16][Dn + 4];

    const float* px = x + (size_t)(I0 + m) * Dn;
    f32x4 acc0 = {0,0,0,0}, acc1 = {0,0,0,0};
    #pragma unroll
    for (int ks = 0; ks < 4; ++ks) {
        int k0 = q * 8 + ks * 32;
        float v[8]; short8 ahi, alo;
        *(float4*)(v)     = *(const float4*)(px + k0);
        *(float4*)(v + 4) = *(const float4*)(px + k0 + 4);
        #pragma unroll
        for (int j = 0; j < 8; ++j) {
            ushort hi = f2bf(v[j]);
            ahi[j] = (short)hi;
            alo[j] = (short)f2bf(v[j] - bf2f(hi));
        }
        #pragma unroll
        for (int nn = 0; nn < 2; ++nn) {
            int brow = (w * 2 + nn) * 16 + m;
            short8 bhi = __builtin_bit_cast(short8, ((const us8*)(Whi + (size_t)brow * Dn))[q + ks * 4]);
            short8 blo = __builtin_bit_cast(short8, ((const us8*)(Wlo + (size_t)brow * Dn))[q + ks * 4]);
            f32x4 acc = nn ? acc1 : acc0;
            acc = __builtin_amdgcn_mfma_f32_16x16x32_bf16(ahi, bhi, acc, 0, 0, 0);
            acc = __builtin_amdgcn_mfma_f32_16x16x32_bf16(alo, bhi, acc, 0, 0, 0);
            acc = __builtin_amdgcn_mfma_f32_16x16x32_bf16(ahi, blo, acc, 0, 0, 0);
            if (nn) acc1 = acc; else acc0 = acc;
        }
    }
    #pragma unroll
    for (int nn = 0; nn < 2; ++nn) {
        int col = (w * 2 + nn) * 16 + m;
        float bias = Wb[col];
        f32x4 acc = nn ? acc1 : acc0;
        #pragma unroll
        for (int r = 0; r < 4; ++r) {
            int rl = q * 4 + r;
            float hv = acc[r] + bias;
            size_t o = (size_t)(I0 + rl) * Dn + col;
            h[o] = hv;
            h16[o] = f2bf(hv);
            hs[rl][col] = hv;
        }
    }
    __syncthreads();

    f32x4 bcc0 = {0,0,0,0}, bcc1 = {0,0,0,0};
    #pragma unroll
    for (int ks = 0; ks < 4; ++ks) {
        int k0 = q * 8 + ks * 32;
        float v[8]; short8 ahi, alo;
        *(float4*)(v)     = *(const float4*)(&hs[m][k0]);
        *(float4*)(v + 4) = *(const float4*)(&hs[m][k0 + 4]);
        #pragma unroll
        for (int j = 0; j < 8; ++j) {
            ushort hi = f2bf(v[j]);
            ahi[j] = (short)hi;
            alo[j] = (short)f2bf(v[j] - bf2f(hi));
        }
        #pragma unroll
        for (int nn = 0; nn < 2; ++nn) {
            int brow = (w * 2 + nn) * 16 + m;
            short8 bhi = __builtin_bit_cast(short8, ((const us8*)(AThi + (size_t)brow * Dn))[q + ks * 4]);
            short8 blo = __builtin_bit_cast(short8, ((const us8*)(ATlo + (size_t)brow * Dn))[q + ks * 4]);
            f32x4 acc = nn ? bcc1 : bcc0;
            acc = __builtin_amdgcn_mfma_f32_16x16x32_bf16(ahi, bhi, acc, 0, 0, 0);
            acc = __builtin_amdgcn_mfma_f32_16x16x32_bf16(alo, bhi, acc, 0, 0, 0);
            acc = __builtin_amdgcn_mfma_f32_16x16x32_bf16(ahi, blo, acc, 0, 0, 0);
            if (nn) bcc1 = acc; else bcc0 = acc;
        }
    }
    #pragma unroll
    for (int nn = 0; nn < 2; ++nn) {
        int col = (w * 2 + nn) * 16 + m;
        f32x4 acc = nn ? bcc1 : bcc0;
        #pragma unroll
        for (int r = 0; r < 4; ++r) {
            int rl = q * 4 + r;
            hA16[(size_t)(I0 + rl) * Dn + col] = f2bf(acc[r]);
        }
    }
}

// ---------------- K3: scores: MFMA -> LDS -> coalesced mask/exp/store + colsum ----------------
__global__ __launch_bounds__(256) void k_scores(const ushort* __restrict__ h16,
                                                const ushort* __restrict__ hA16,
                                                const float* __restrict__ adj,
                                                ushort* __restrict__ E,
                                                float* __restrict__ Z) {
    int b  = blockIdx.z;
    int I0 = blockIdx.x * 64;
    int J0 = blockIdx.y * 64;
    int t = threadIdx.x, wid = t >> 6, lane = t & 63;
    int m = lane & 15, q = lane >> 4;

    __shared__ float sc[64][68];
    __shared__ float cz[4][64];

    const size_t hb = (size_t)b * Nn * Dn;
    int rowA = I0 + wid * 16 + m;
    const us8* pA1 = (const us8*)(hA16 + hb + (size_t)rowA * Dn);
    const us8* pA2 = (const us8*)(h16  + hb + (size_t)rowA * Dn);
    const us8* pBh[4]; const us8* pBa[4];
    #pragma unroll
    for (int nt = 0; nt < 4; ++nt) {
        int rb = J0 + nt * 16 + m;
        pBh[nt] = (const us8*)(h16  + hb + (size_t)rb * Dn);
        pBa[nt] = (const us8*)(hA16 + hb + (size_t)rb * Dn);
    }

    f32x4 acc[4] = {};
    #pragma unroll
    for (int ks = 0; ks < 4; ++ks) {
        int idx = q + ks * 4;
        short8 a1 = __builtin_bit_cast(short8, pA1[idx]);
        short8 a2 = __builtin_bit_cast(short8, pA2[idx]);
        #pragma unroll
        for (int nt = 0; nt < 4; ++nt) {
            short8 b1 = __builtin_bit_cast(short8, pBh[nt][idx]);
            short8 b2 = __builtin_bit_cast(short8, pBa[nt][idx]);
            acc[nt] = __builtin_amdgcn_mfma_f32_16x16x32_bf16(a1, b1, acc[nt], 0, 0, 0);
            acc[nt] = __builtin_amdgcn_mfma_f32_16x16x32_bf16(a2, b2, acc[nt], 0, 0, 0);
        }
    }
    #pragma unroll
    for (int nt = 0; nt < 4; ++nt)
        #pragma unroll
        for (int r = 0; r < 4; ++r)
            sc[wid * 16 + q * 4 + r][nt * 16 + m] = acc[nt][r];
    __syncthreads();

    // coalesced streaming pass: 4 iters x (16 rows x 16 float4-cols)
    int row16 = t >> 4, c = t & 15;
    float colsum[4] = {0.f, 0.f, 0.f, 0.f};
    size_t adjbase = ((size_t)b * Nn + I0) * Nn + J0;
    #pragma unroll
    for (int it = 0; it < 4; ++it) {
        int row = it * 16 + row16;
        float a4[4], s4[4];
        *(float4*)a4 = *(const float4*)(adj + adjbase + (size_t)row * Nn + c * 4);
        *(float4*)s4 = *(const float4*)(&sc[row][c * 4]);
        us4 e4;
        #pragma unroll
        for (int j = 0; j < 4; ++j) {
            float ex = __expf(s4[j]);
            bool on = a4[j] > 0.f;
            e4[j] = f2bf(on ? ex : 0.f);
            colsum[j] += on ? (ex - 1.0f) : 0.f;
        }
        *(us4*)(E + ((size_t)b * Nn + I0 + row) * Nn + J0 + c * 4) = e4;
    }
    #pragma unroll
    for (int j = 0; j < 4; ++j) {
        colsum[j] += __shfl_xor(colsum[j], 16, 64);
        colsum[j] += __shfl_xor(colsum[j], 32, 64);
    }
    if (lane < 16) {
        #pragma unroll
        for (int j = 0; j < 4; ++j) cz[wid][lane * 4 + j] = colsum[j];
    }
    __syncthreads();
    if (t < 64) {
        float s = cz[0][t] + cz[1][t] + cz[2][t] + cz[3][t];
        atomicAdd(&Z[b * Nn + J0 + t], s);
    }
}

// ---------------- K4: T[k][j] = src[j][k] / Z[j]  (bf16, transposed) ----------------
__global__ __launch_bounds__(256) void k_prep(const float* __restrict__ src,
                                              const float* __restrict__ Z,
                                              ushort* __restrict__ T) {
    int b = blockIdx.y;
    int j0 = blockIdx.x * 64;
    int t = threadIdx.x;
    __shared__ float ls[64][129];
    __shared__ float iz[64];
    if (t < 64) iz[t] = 1.0f / Z[b * Nn + j0 + t];
    __syncthreads();
    #pragma unroll
    for (int it = 0; it < 32; ++it) {
        int idx = it * 256 + t;
        int j = idx >> 7, k = idx & 127;
        ls[j][k] = src[((size_t)b * Nn + j0 + j) * Dn + k] * iz[j];
    }
    __syncthreads();
    #pragma unroll
    for (int it = 0; it < 32; ++it) {
        int idx = it * 256 + t;
        int k = idx >> 6, j = idx & 63;
        T[((size_t)b * Dn + k) * Nn + j0 + j] = f2bf(ls[j][k]);
    }
}

// ---------------- K5: hop: az = E @ T^T (waves split K, exact E traffic),
//                  fused relu + gate + lerp; writes next T (bf16) or final out (f32) -------
__global__ __launch_bounds__(256) void k_hop(const ushort* __restrict__ E,
                                             const ushort* __restrict__ T,
                                             const float* __restrict__ h,
                                             const float* __restrict__ Z,
                                             const float* __restrict__ gw,
                                             const float* __restrict__ gb,
                                             ushort* __restrict__ Tnext,
                                             float* __restrict__ out,
                                             int last) {
    int b  = blockIdx.y;
    int I0 = blockIdx.x * 16;
    int t = threadIdx.x, w = t >> 6, lane = t & 63;
    int m = lane & 15, q = lane >> 4;

    __shared__ float red[4][16][136];   // pad 136: 2-way banks max on reduce read
    __shared__ ushort tt[128 * 16];

    const us8* pA = (const us8*)(E + ((size_t)b * Nn + I0 + m) * Nn);
    const us8* pB[8];
    #pragma unroll
    for (int nt = 0; nt < 8; ++nt)
        pB[nt] = (const us8*)(T + ((size_t)b * Dn + nt * 16 + m) * Nn);

    f32x4 acc[8] = {};
    #pragma unroll
    for (int ks = 0; ks < 8; ++ks) {         // this wave's K-quarter: 256 elems
        int idx = w * 32 + ks * 4 + q;
        short8 a = __builtin_bit_cast(short8, pA[idx]);
        #pragma unroll
        for (int nt = 0; nt < 8; ++nt)
            acc[nt] = __builtin_amdgcn_mfma_f32_16x16x32_bf16(
                a, __builtin_bit_cast(short8, pB[nt][idx]), acc[nt], 0, 0, 0);
    }
    #pragma unroll
    for (int nt = 0; nt < 8; ++nt)
        #pragma unroll
        for (int r = 0; r < 4; ++r)
            red[w][q * 4 + r][nt * 16 + m] = acc[nt][r];
    __syncthreads();

    int row = t >> 4, c = t & 15;
    float gb0 = gb[0];
    float azv[8], hv[8];
    float gsum = 0.f;
    size_t hbase = ((size_t)b * Nn + I0 + row) * Dn;
    #pragma unroll
    for (int j = 0; j < 8; ++j) {
        int k = c + 16 * j;
        float v = red[0][row][k] + red[1][row][k] + red[2][row][k] + red[3][row][k];
        v = fmaxf(v, 0.f);
        float hh = h[hbase + k];
        azv[j] = v; hv[j] = hh;
        gsum += hh * gw[k] + v * gw[Dn + k];
    }
    gsum += __shfl_xor(gsum, 1, 64);
    gsum += __shfl_xor(gsum, 2, 64);
    gsum += __shfl_xor(gsum, 4, 64);
    gsum += __shfl_xor(gsum, 8, 64);
    float coef = 1.0f / (1.0f + __expf(-(gsum + gb0)));

    if (last) {
        #pragma unroll
        for (int j = 0; j < 8; ++j)
            out[hbase + c + 16 * j] = coef * hv[j] + (1.f - coef) * azv[j];
    } else {
        float iz = 1.0f / Z[b * Nn + I0 + row];
        #pragma unroll
        for (int j = 0; j < 8; ++j) {
            int k = c + 16 * j;
            tt[k * 16 + row] = f2bf((coef * hv[j] + (1.f - coef) * azv[j]) * iz);
        }
        __syncthreads();
        int k2 = t >> 1, r0 = (t & 1) * 8;   // each thread: 8 ushorts = 16 B
        *(us8*)(Tnext + ((size_t)b * Dn + k2) * Nn + I0 + r0) = *(const us8*)(&tt[k2 * 16 + r0]);
    }
}

extern "C" void kernel_launch(void* const* d_in, const int* in_sizes, int n_in,
                              void* d_out, int out_size, void* d_ws, size_t ws_size,
                              hipStream_t stream) {
    const float* x    = (const float*)d_in[0];   // [B,N,128]
    const float* adj  = (const float*)d_in[1];   // [B,N,N]
    const float* Ww   = (const float*)d_in[2];   // [128,128]
    const float* Wb   = (const float*)d_in[3];   // [128]
    const float* A    = (const float*)d_in[4];   // [128,128]
    const float* gw   = (const float*)d_in[5];   // [1,256]
    const float* gb   = (const float*)d_in[6];   // [1]
    float* out = (float*)d_out;                  // [B,N,128] f32

    char* ws = (char*)d_ws;
    float*  h    = (float*)(ws);                          // 8 MB f32
    ushort* h16  = (ushort*)(ws + (8u << 20));            // 4 MB bf16 (dead after k_scores)
    ushort* hA16 = (ushort*)(ws + (12u << 20));           // 4 MB bf16 (dead after k_scores)
    ushort* Ta   = (ushort*)(ws + (8u << 20));            // aliases h16
    ushort* Tb   = (ushort*)(ws + (12u << 20));           // aliases hA16
    ushort* E    = (ushort*)(ws + (16u << 20));           // 32 MB bf16
    float*  Z    = (float*)(ws + (48u << 20));            // 64 KB
    ushort* Whi  = (ushort*)(ws + (48u << 20) + (64u << 10));
    ushort* Wlo  = (ushort*)(ws + (48u << 20) + (96u << 10));
    ushort* AThi = (ushort*)(ws + (48u << 20) + (128u << 10));
    ushort* ATlo = (ushort*)(ws + (48u << 20) + (160u << 10));
    // total ~48.2 MB

    k_wprep <<<64, 256, 0, stream>>>(Ww, A, Whi, Wlo, AThi, ATlo, Z);
    k_h     <<<1024, 256, 0, stream>>>(x, Wb, Whi, Wlo, AThi, ATlo, h, h16, hA16);
    k_scores<<<dim3(16, 16, Bn), 256, 0, stream>>>(h16, hA16, adj, E, Z);
    k_prep  <<<dim3(16, Bn), 256, 0, stream>>>(h, Z, Ta);          // T0 = h/Z
    k_hop   <<<dim3(64, Bn), 256, 0, stream>>>(E, Ta, h, Z, gw, gb, Tb, out, 0);
    k_hop   <<<dim3(64, Bn), 256, 0, stream>>>(E, Tb, h, Z, gw, gb, Ta, out, 0);
    k_hop   <<<dim3(64, Bn), 256, 0, stream>>>(E, Ta, h, Z, gw, gb, (ushort*)nullptr, out, 1);
}